// Round 4
// baseline (3012.159 us; speedup 1.0000x reference)
//
#include <hip/hip_runtime.h>
#include <math.h>
#include <stdint.h>

typedef __bf16 bf16_t;
typedef __bf16 bf16x8 __attribute__((ext_vector_type(8)));
typedef __bf16 bf16x4 __attribute__((ext_vector_type(4)));
typedef float f32x4 __attribute__((ext_vector_type(4)));

#define NLAYER 6
#define DMODEL 768
#define NHEAD 12
#define DHEAD 64
#define SEQ 512
#define BATCH 8
#define MROWS 4096 /* BATCH*SEQ */
#define DFFN 3072

// ---------- helpers ----------

__device__ inline void async_load16(const void* g, void* lds) {
  const __attribute__((address_space(1))) void* gp =
      (const __attribute__((address_space(1))) void*)(uintptr_t)g;
  __attribute__((address_space(3))) void* lp =
      (__attribute__((address_space(3))) void*)(uint32_t)(uintptr_t)lds;
  __builtin_amdgcn_global_load_lds(gp, lp, 16, 0, 0);
}

#define VMCNT(n) __builtin_amdgcn_s_waitcnt(0x0F70 | (n))

__device__ inline float wsum(float v) {
#pragma unroll
  for (int o = 32; o > 0; o >>= 1) v += __shfl_xor(v, o, 64);
  return v;
}

__device__ inline float gelu_f(float x) {
  float u = 0.7978845608028654f * (x + 0.044715f * x * x * x);
  return 0.5f * x * (1.0f + tanhf(u));
}

struct GP {
  const bf16_t* A;
  const bf16_t* B;
  const float* bias;   // [N] or null (ignored when ksplit>1)
  const float* resid;  // f32, ldc layout, or null
  float* outF;         // f32 out (or partial base when ksplit>1)
  bf16_t* outB;        // bf16 out or null
  int M, N, K;
  int lda, ldb, ldc;
  long pstride;  // partial-buffer stride (elements) for ksplit>1
  int act;       // 1 = gelu
  int ksplit;
};

// ---------- 128x128 GEMM (round-0 proven kernel, N=768/1536 shapes) ----------
__global__ __launch_bounds__(256) void gemm128(GP p) {
  __shared__ __align__(16) bf16_t As[2][128 * 32];
  __shared__ __align__(16) bf16_t Bs[2][128 * 32];
  const int tid = threadIdx.x;
  const int wave = tid >> 6, lane = tid & 63;
  const int wr = wave >> 1, wc = wave & 1;
  const int lrow = lane & 15, kq = lane >> 4;
  const int sr = tid >> 2;
  const int sc = (tid & 3) << 3;
  const int m0 = blockIdx.x * 128;
  const int n0 = blockIdx.y * 128;
  const int zs = (int)blockIdx.z;

  const int kc = p.K / p.ksplit;
  const int kstart = zs * kc;
  const int kend = kstart + kc;

  auto stage = [&](int k0, int buf) {
#pragma unroll
    for (int r = 0; r < 2; ++r)
      async_load16(p.A + (long)(m0 + r * 64 + sr) * p.lda + (k0 + sc),
                   &As[buf][(r * 64 + wave * 16) * 32]);
#pragma unroll
    for (int r = 0; r < 2; ++r)
      async_load16(p.B + (long)(n0 + r * 64 + sr) * p.ldb + (k0 + sc),
                   &Bs[buf][(r * 64 + wave * 16) * 32]);
  };

  f32x4 acc[4][4] = {};
  stage(kstart, 0);
  int cur = 0;

  for (int k0 = kstart; k0 < kend; k0 += 32) {
    const bool hn = (k0 + 32) < kend;
    if (hn) {
      stage(k0 + 32, cur ^ 1);
      __builtin_amdgcn_s_waitcnt(0xF74);  // vmcnt(4): cur buf's 4 loads done
    } else {
      __builtin_amdgcn_s_waitcnt(0xF70);  // vmcnt(0)
    }
    __builtin_amdgcn_s_barrier();

    bf16x8 af[4], bfr[4];
#pragma unroll
    for (int i = 0; i < 4; ++i)
      af[i] = *(const bf16x8*)&As[cur][(wr * 64 + i * 16 + lrow) * 32 + kq * 8];
#pragma unroll
    for (int j = 0; j < 4; ++j)
      bfr[j] = *(const bf16x8*)&Bs[cur][(wc * 64 + j * 16 + lrow) * 32 + kq * 8];
#pragma unroll
    for (int i = 0; i < 4; ++i)
#pragma unroll
      for (int j = 0; j < 4; ++j)
        acc[i][j] = __builtin_amdgcn_mfma_f32_16x16x32_bf16(af[i], bfr[j], acc[i][j], 0, 0, 0);

    __builtin_amdgcn_s_barrier();
    cur ^= 1;
  }

  const int crow0 = m0 + wr * 64 + kq * 4;
  const int ccol0 = n0 + wc * 64 + lrow;
  if (p.ksplit > 1) {
    float* po = p.outF + (long)zs * p.pstride;
#pragma unroll
    for (int j = 0; j < 4; ++j) {
      const int col = ccol0 + j * 16;
#pragma unroll
      for (int i = 0; i < 4; ++i)
#pragma unroll
        for (int r = 0; r < 4; ++r)
          po[(long)(crow0 + i * 16 + r) * p.ldc + col] = acc[i][j][r];
    }
  } else {
#pragma unroll
    for (int j = 0; j < 4; ++j) {
      const int col = ccol0 + j * 16;
#pragma unroll
      for (int i = 0; i < 4; ++i) {
#pragma unroll
        for (int r = 0; r < 4; ++r) {
          const int row = crow0 + i * 16 + r;
          const long idx = (long)row * p.ldc + col;
          float y = acc[i][j][r];
          if (p.bias) y += p.bias[col];
          if (p.resid) y += p.resid[idx];
          if (p.act) y = gelu_f(y);
          if (p.outF) p.outF[idx] = y;
          if (p.outB) p.outB[idx] = (bf16_t)y;
        }
      }
    }
  }
}

// ---------- 256x256 GEMM v2 ----------
// BK=64, 512 threads (8 waves 2Mx4N, wave-out 128x64). LDS: A [2][256][64] +
// B [2][256][64] bf16 = 128 KiB. Row-major 128B rows; each global_load_lds
// stages 8 FULL rows (8x128B cachelines, coalesced). Swizzle: 16B-slot s at
// row r stored at s^(r&7) (32-bank spread for the 16-row column reads);
// staged via inverse-swizzled global source + linear LDS dest.
// Sync per K-tile: barrier; stage(next->other buf); vmcnt(8) [waits loads
// issued one full compute-phase ago]; barrier; compute. Loop unrolled x2 so
// buffer index is compile-time (no runtime-indexed LDS addressing).
__global__ __launch_bounds__(512) void gemm256(GP p) {
  __shared__ __align__(16) bf16_t Ls[65536];  // A: d*16384; B: 32768 + d*16384
  const int tid = threadIdx.x;
  const int wave = tid >> 6, lane = tid & 63;
  const int wr = wave >> 2, wc = wave & 3;  // 2 x 4 wave grid
  const int lrow = lane & 15, kq = lane >> 4;
  const int m0 = blockIdx.x * 256;
  const int n0 = blockIdx.y * 256;
  const int zs = (int)blockIdx.z;
  const int kc = p.K / p.ksplit;
  const int kstart = zs * kc;
  const int NT = kc >> 6;  // K-tiles of 64 (always 12 here, even)

  // staging: call c covers rows c*64 + wave*8 + (l>>3); lane writes LDS slot
  // l&7 (linear dest); source data slot = (l&7)^((l>>3)&7) (inverse swizzle).
  const int srow = wave * 8 + (lane >> 3);
  const int sslot = ((lane & 7) ^ ((lane >> 3) & 7)) * 8;
  const bf16_t* gA0 = p.A + (long)(m0 + srow) * p.lda + sslot + kstart;
  const bf16_t* gB0 = p.B + (long)(n0 + srow) * p.ldb + sslot + kstart;
  const long c64a = (long)64 * p.lda, c64b = (long)64 * p.ldb;
  const bf16_t* gA[4] = {gA0, gA0 + c64a, gA0 + 2 * c64a, gA0 + 3 * c64a};
  const bf16_t* gB[4] = {gB0, gB0 + c64b, gB0 + 2 * c64b, gB0 + 3 * c64b};
  const int ldsW = wave * 512;  // + d*16384 + c*4096 (+32768 for B)

  // reads: row = (base rows multiple of 8) + lrow; data slot s = kk*4+kq at
  // LDS slot s^(lrow&7).
  const int ra = (wr * 128 + lrow) * 64;  // + d*16384 + mi*1024 + sw[kk]
  const int rb = (wc * 64 + lrow) * 64;   // + 32768 + d*16384 + j*1024 + sw[kk]
  const int sw0 = ((kq ^ (lrow & 7))) * 8;
  const int sw1 = (((4 + kq) ^ (lrow & 7))) * 8;

  f32x4 acc[8][4] = {};

#define STAGE256(d, t)                                                       \
  do {                                                                       \
    _Pragma("unroll") for (int c_ = 0; c_ < 4; ++c_)                         \
        async_load16(gA[c_] + (t) * 64, &Ls[(d)*16384 + ldsW + c_ * 4096]);  \
    _Pragma("unroll") for (int c_ = 0; c_ < 4; ++c_) async_load16(           \
        gB[c_] + (t) * 64, &Ls[32768 + (d)*16384 + ldsW + c_ * 4096]);       \
  } while (0)

#define COMPUTE256(d)                                                        \
  do {                                                                       \
    _Pragma("unroll") for (int kk = 0; kk < 2; ++kk) {                       \
      const int sw_ = kk ? sw1 : sw0;                                        \
      bf16x8 bv[4];                                                          \
      _Pragma("unroll") for (int j = 0; j < 4; ++j) bv[j] =                  \
          *(const bf16x8*)&Ls[32768 + (d)*16384 + rb + j * 1024 + sw_];      \
      _Pragma("unroll") for (int mi = 0; mi < 8; ++mi) {                     \
        const bf16x8 av =                                                    \
            *(const bf16x8*)&Ls[(d)*16384 + ra + mi * 1024 + sw_];           \
        _Pragma("unroll") for (int j = 0; j < 4; ++j) acc[mi][j] =           \
            __builtin_amdgcn_mfma_f32_16x16x32_bf16(av, bv[j], acc[mi][j],   \
                                                    0, 0, 0);                \
      }                                                                      \
    }                                                                        \
  } while (0)

  STAGE256(0, 0);
  const int NI = NT >> 1;
  for (int it = 0; it < NI; ++it) {
    const int t1 = 2 * it + 1;
    const int t2 = (2 * it + 2 < NT) ? 2 * it + 2 : 0;  // wrap tail, unused
    // tile 2it from buf0; prefetch t1 -> buf1
    __builtin_amdgcn_s_barrier();  // buf1 readers (prev iter) done
    STAGE256(1, t1);
    VMCNT(8);  // buf0's 8 loads (issued a full phase ago) landed
    __builtin_amdgcn_s_barrier();
    __builtin_amdgcn_sched_barrier(0);
    COMPUTE256(0);
    // tile 2it+1 from buf1; prefetch t2 -> buf0
    __builtin_amdgcn_s_barrier();  // buf0 readers done
    STAGE256(0, t2);
    VMCNT(8);
    __builtin_amdgcn_s_barrier();
    __builtin_amdgcn_sched_barrier(0);
    COMPUTE256(1);
  }
  VMCNT(0);  // drain wrapped tail stages before retire

  const int crow0 = m0 + wr * 128 + kq * 4;
  const int ccol0 = n0 + wc * 64 + lrow;
  if (p.ksplit > 1) {
    float* po = p.outF + (long)zs * p.pstride;
#pragma unroll
    for (int j = 0; j < 4; ++j) {
      const int col = ccol0 + j * 16;
#pragma unroll
      for (int i = 0; i < 8; ++i)
#pragma unroll
        for (int r = 0; r < 4; ++r)
          po[(long)(crow0 + i * 16 + r) * p.ldc + col] = acc[i][j][r];
    }
  } else {
#pragma unroll
    for (int j = 0; j < 4; ++j) {
      const int col = ccol0 + j * 16;
#pragma unroll
      for (int i = 0; i < 8; ++i) {
#pragma unroll
        for (int r = 0; r < 4; ++r) {
          const int row = crow0 + i * 16 + r;
          const long idx = (long)row * p.ldc + col;
          float y = acc[i][j][r];
          if (p.bias) y += p.bias[col];
          if (p.resid) y += p.resid[idx];
          if (p.act) y = gelu_f(y);
          if (p.outF) p.outF[idx] = y;
          if (p.outB) p.outB[idx] = (bf16_t)y;
        }
      }
    }
  }
#undef STAGE256
#undef COMPUTE256
}

// ---------- fused flash attention ----------
#define QT 64
#define KT 128
#define VPAD 136

__global__ __launch_bounds__(256) void attn_kernel(const bf16_t* __restrict__ qkv,
                                                   const int* __restrict__ toks,
                                                   bf16_t* __restrict__ ctx, int causal) {
  __shared__ __align__(16) bf16_t Qs[QT * 64];
  __shared__ __align__(16) bf16_t Ks[KT * 64];
  __shared__ __align__(16) bf16_t Vs[64 * VPAD];
  __shared__ __align__(16) bf16_t Ps[QT * VPAD];
  __shared__ int Ts[SEQ];
  const int tid = threadIdx.x;
  const int wave = tid >> 6, lane = tid & 63;
  const int lm = lane & 15, lq = lane >> 4;
  const int q0 = blockIdx.x * QT;
  const int bh = blockIdx.y;
  const int b = bh / NHEAD, h = bh % NHEAD;
  const long rowbase = (long)b * SEQ;
  const int LD = 3 * DMODEL;
  const bf16_t* Qg = qkv + (rowbase + q0) * LD + h * DHEAD;
  const bf16_t* Kg = qkv + rowbase * LD + DMODEL + h * DHEAD;
  const bf16_t* Vg = qkv + rowbase * LD + 2 * DMODEL + h * DHEAD;

  Ts[tid] = toks[b * SEQ + tid];
  Ts[tid + 256] = toks[b * SEQ + tid + 256];

#pragma unroll
  for (int r = 0; r < 2; ++r) {
    const int c = r * 256 + tid;
    const int row = c >> 3, c8 = (c & 7) * 8;
    async_load16(Qg + (long)row * LD + c8, &Qs[c * 8]);
  }
  __syncthreads();

  bf16x8 aQ0 = *(const bf16x8*)&Qs[(wave * 16 + lm) * 64 + lq * 8];
  bf16x8 aQ1 = *(const bf16x8*)&Qs[(wave * 16 + lm) * 64 + 32 + lq * 8];

  float m_i[4], l_i[4];
  f32x4 O[4] = {};
#pragma unroll
  for (int r = 0; r < 4; ++r) { m_i[r] = -3.0e38f; l_i[r] = 0.0f; }

  const int s_end = causal ? (q0 + QT) : SEQ;
  for (int s0 = 0; s0 < s_end; s0 += KT) {
    __syncthreads();
#pragma unroll
    for (int r = 0; r < 4; ++r) {
      const int c = r * 256 + tid;
      const int row = c >> 3, c8 = (c & 7) * 8;
      async_load16(Kg + (long)(s0 + row) * LD + c8, &Ks[c * 8]);
    }
#pragma unroll
    for (int r = 0; r < 4; ++r) {
      const int c = r * 256 + tid;
      const int row = c >> 3, c8 = (c & 7) * 8;
      const bf16x8 vv = *(const bf16x8*)(Vg + (long)(s0 + row) * LD + c8);
#pragma unroll
      for (int j = 0; j < 8; ++j) Vs[(c8 + j) * VPAD + row] = vv[j];
    }
    __syncthreads();

    f32x4 sv[8];
#pragma unroll
    for (int jt = 0; jt < 8; ++jt) {
      const bf16x8 b0 = *(const bf16x8*)&Ks[(jt * 16 + lm) * 64 + lq * 8];
      const bf16x8 b1 = *(const bf16x8*)&Ks[(jt * 16 + lm) * 64 + 32 + lq * 8];
      f32x4 a = {};
      a = __builtin_amdgcn_mfma_f32_16x16x32_bf16(aQ0, b0, a, 0, 0, 0);
      a = __builtin_amdgcn_mfma_f32_16x16x32_bf16(aQ1, b1, a, 0, 0, 0);
      sv[jt] = a;
    }

#pragma unroll
    for (int r = 0; r < 4; ++r) {
      const int qa = q0 + wave * 16 + lq * 4 + r;
      float sr[8];
      float mx = -3.0e38f;
#pragma unroll
      for (int jt = 0; jt < 8; ++jt) {
        const int k = s0 + jt * 16 + lm;
        const float x = sv[jt][r] * 0.125f;
        const bool msk = (Ts[k] == 0) || (causal && (k > qa));
        sr[jt] = msk ? -1.0e18f : x;
        mx = fmaxf(mx, sr[jt]);
      }
#pragma unroll
      for (int o = 1; o < 16; o <<= 1) mx = fmaxf(mx, __shfl_xor(mx, o, 64));
      const float mn = fmaxf(m_i[r], mx);
      const float alpha = __expf(m_i[r] - mn);
      float sum = 0.0f;
#pragma unroll
      for (int jt = 0; jt < 8; ++jt) {
        const float pv = __expf(sr[jt] - mn);
        sr[jt] = pv;
        sum += pv;
      }
#pragma unroll
      for (int o = 1; o < 16; o <<= 1) sum += __shfl_xor(sum, o, 64);
      l_i[r] = l_i[r] * alpha + sum;
      m_i[r] = mn;
#pragma unroll
      for (int jn = 0; jn < 4; ++jn) O[jn][r] *= alpha;
#pragma unroll
      for (int jt = 0; jt < 8; ++jt)
        Ps[(wave * 16 + lq * 4 + r) * VPAD + jt * 16 + lm] = (bf16_t)sr[jt];
    }

#pragma unroll
    for (int kt = 0; kt < 4; ++kt) {
      const bf16x8 aP = *(const bf16x8*)&Ps[(wave * 16 + lm) * VPAD + kt * 32 + lq * 8];
#pragma unroll
      for (int jn = 0; jn < 4; ++jn) {
        const bf16x8 bV = *(const bf16x8*)&Vs[(jn * 16 + lm) * VPAD + kt * 32 + lq * 8];
        O[jn] = __builtin_amdgcn_mfma_f32_16x16x32_bf16(aP, bV, O[jn], 0, 0, 0);
      }
    }
  }

#pragma unroll
  for (int r = 0; r < 4; ++r) {
    const int q = q0 + wave * 16 + lq * 4 + r;
    const float inv = 1.0f / l_i[r];
#pragma unroll
    for (int jn = 0; jn < 4; ++jn) {
      const int d = jn * 16 + lm;
      ctx[(rowbase + q) * DMODEL + h * DHEAD + d] = (bf16_t)(O[jn][r] * inv);
    }
  }
}

// ---------- LayerNorm (row = 768) ----------
__global__ __launch_bounds__(256) void ln_kernel(const float* __restrict__ X,
                                                 const float* __restrict__ g,
                                                 const float* __restrict__ b,
                                                 bf16_t* __restrict__ outB,
                                                 float* __restrict__ outF) {
  const int row = blockIdx.x, tid = threadIdx.x;
  const float* xr = X + (long)row * DMODEL;
  const float v0 = xr[tid], v1 = xr[tid + 256], v2 = xr[tid + 512];
  __shared__ float r1[4], r2[4];
  const int wv = tid >> 6, ln = tid & 63;
  float s = wsum(v0 + v1 + v2);
  if (ln == 0) r1[wv] = s;
  __syncthreads();
  const float mean = (r1[0] + r1[1] + r1[2] + r1[3]) * (1.0f / DMODEL);
  const float d0 = v0 - mean, d1 = v1 - mean, d2 = v2 - mean;
  float q = wsum(d0 * d0 + d1 * d1 + d2 * d2);
  if (ln == 0) r2[wv] = q;
  __syncthreads();
  const float var = (r2[0] + r2[1] + r2[2] + r2[3]) * (1.0f / DMODEL);
  const float rs = rsqrtf(var + 1e-6f);
  const float y0 = d0 * rs * g[tid] + b[tid];
  const float y1 = d1 * rs * g[tid + 256] + b[tid + 256];
  const float y2 = d2 * rs * g[tid + 512] + b[tid + 512];
  const long base = (long)row * DMODEL;
  if (outB) {
    outB[base + tid] = (bf16_t)y0;
    outB[base + tid + 256] = (bf16_t)y1;
    outB[base + tid + 512] = (bf16_t)y2;
  }
  if (outF) {
    outF[base + tid] = y0;
    outF[base + tid + 256] = y1;
    outF[base + tid + 512] = y2;
  }
}

// ---------- reduce split-K partials + bias + residual, then LayerNorm ----------
__global__ __launch_bounds__(256) void reduce_ln_kernel(
    const float* __restrict__ parts, long pstr, int np,
    const float* __restrict__ bias, float* __restrict__ res,
    const float* __restrict__ g, const float* __restrict__ b,
    bf16_t* __restrict__ outB, float* __restrict__ outF) {
  const int row = blockIdx.x, tid = threadIdx.x;
  const long base = (long)row * DMODEL;
  float v0, v1, v2;
  {
    float t0 = res[base + tid] + bias[tid];
    float t1 = res[base + tid + 256] + bias[tid + 256];
    float t2 = res[base + tid + 512] + bias[tid + 512];
    for (int p = 0; p < np; ++p) {
      const float* pp = parts + p * pstr + base;
      t0 += pp[tid];
      t1 += pp[tid + 256];
      t2 += pp[tid + 512];
    }
    v0 = t0; v1 = t1; v2 = t2;
    res[base + tid] = t0;
    res[base + tid + 256] = t1;
    res[base + tid + 512] = t2;
  }
  __shared__ float r1[4], r2[4];
  const int wv = tid >> 6, ln = tid & 63;
  float s = wsum(v0 + v1 + v2);
  if (ln == 0) r1[wv] = s;
  __syncthreads();
  const float mean = (r1[0] + r1[1] + r1[2] + r1[3]) * (1.0f / DMODEL);
  const float d0 = v0 - mean, d1 = v1 - mean, d2 = v2 - mean;
  float q = wsum(d0 * d0 + d1 * d1 + d2 * d2);
  if (ln == 0) r2[wv] = q;
  __syncthreads();
  const float var = (r2[0] + r2[1] + r2[2] + r2[3]) * (1.0f / DMODEL);
  const float rs = rsqrtf(var + 1e-6f);
  const float y0 = d0 * rs * g[tid] + b[tid];
  const float y1 = d1 * rs * g[tid + 256] + b[tid + 256];
  const float y2 = d2 * rs * g[tid + 512] + b[tid + 512];
  if (outB) {
    outB[base + tid] = (bf16_t)y0;
    outB[base + tid + 256] = (bf16_t)y1;
    outB[base + tid + 512] = (bf16_t)y2;
  }
  if (outF) {
    outF[base + tid] = y0;
    outF[base + tid + 256] = y1;
    outF[base + tid + 512] = y2;
  }
}

// ---------- reduce split-K partials + bias -> strided bf16 (CA-q into qkv) ----------
__global__ __launch_bounds__(256) void reduce_cvtq_kernel(
    const float* __restrict__ parts, long pstr, int np,
    const float* __restrict__ bias, bf16_t* __restrict__ o) {
  const int row = blockIdx.x, tid = threadIdx.x;
  const long base = (long)row * DMODEL;
  const long ob = (long)row * 3 * DMODEL;
#pragma unroll
  for (int c = 0; c < 3; ++c) {
    const int col = tid + c * 256;
    float t = bias[col];
    for (int p = 0; p < np; ++p) t += parts[p * pstr + base + col];
    o[ob + col] = (bf16_t)t;
  }
}

// ---------- embedding * sqrt(D) + sinusoidal PE ----------
__global__ __launch_bounds__(256) void emb_kernel(const int* __restrict__ tgt,
                                                  const float* __restrict__ tab,
                                                  float* __restrict__ res) {
  const int row = blockIdx.x;
  const int t = row & (SEQ - 1);
  const long tok = tgt[row];
  const float* er = tab + tok * DMODEL;
  float* orow = res + (long)row * DMODEL;
  const float c1 = -9.210340371976184f / 768.0f;
  for (int c = threadIdx.x; c < DMODEL; c += 256) {
    const float e = er[c] * 27.712812921102035f;
    const float div = expf((float)(c & ~1) * c1);
    const float ang = (float)t * div;
    const float pe = (c & 1) ? cosf(ang) : sinf(ang);
    orow[c] = e + pe;
  }
}

// ---------- f32 -> bf16 convert (n4 = n/4) ----------
__global__ __launch_bounds__(256) void cvt_kernel(const float* __restrict__ in,
                                                  bf16_t* __restrict__ o, int n4) {
  const int i = blockIdx.x * 256 + threadIdx.x;
  if (i < n4) {
    const float4 v = ((const float4*)in)[i];
    bf16x4 r = {(bf16_t)v.x, (bf16_t)v.y, (bf16_t)v.z, (bf16_t)v.w};
    ((bf16x4*)o)[i] = r;
  }
}

// ---------- host ----------
extern "C" void kernel_launch(void* const* d_in, const int* in_sizes, int n_in,
                              void* d_out, int out_size, void* d_ws, size_t ws_size,
                              hipStream_t stream) {
  (void)in_sizes; (void)n_in; (void)out_size; (void)ws_size;
  const int* tgt = (const int*)d_in[0];
  const int* srct = (const int*)d_in[1];
  const float* memb = (const float*)d_in[2];
  const float* embt = (const float*)d_in[3];
  const float* sa_w = (const float*)d_in[4];
  const float* sa_b = (const float*)d_in[5];
  const float* ca_w = (const float*)d_in[6];
  const float* ca_b = (const float*)d_in[7];
  const float* ln_g = (const float*)d_in[8];
  const float* ln_b = (const float*)d_in[9];
  const float* ff_w1 = (const float*)d_in[10];
  const float* ff_b1 = (const float*)d_in[11];
  const float* ff_w2 = (const float*)d_in[12];
  const float* ff_b2 = (const float*)d_in[13];
  const float* out_g = (const float*)d_in[14];
  const float* out_b = (const float*)d_in[15];
  float* out = (float*)d_out;

  char* wsb = (char*)d_ws;
  size_t off = 0;
  auto alloc = [&](size_t bytes) -> void* {
    void* pp = wsb + off;
    off = (off + bytes + 255) & ~(size_t)255;
    return pp;
  };
  // NOTE: allocation ORDER and SIZES are load-bearing: FFN2 uses ksplit=4 and
  // its partials span parts(2*PSTR) + xb + qkvb exactly (both dead at that point).
  float* res = (float*)alloc((size_t)MROWS * DMODEL * 4);
  float* parts = (float*)alloc((size_t)2 * MROWS * DMODEL * 4);  // split-K partials 0..1
  bf16_t* xb = (bf16_t*)alloc((size_t)MROWS * DMODEL * 2);       // = parts[2] during FFN2
  bf16_t* qkvb = (bf16_t*)alloc((size_t)MROWS * 3 * DMODEL * 2); // = parts[3] during FFN2
  bf16_t* ctxb = (bf16_t*)alloc((size_t)MROWS * DMODEL * 2);
  bf16_t* membb = (bf16_t*)alloc((size_t)MROWS * DMODEL * 2);
  bf16_t* ffh = (bf16_t*)alloc((size_t)MROWS * DFFN * 2);
  bf16_t* wA = (bf16_t*)alloc((size_t)4 * DMODEL * DMODEL * 2);
  bf16_t* wF1 = (bf16_t*)alloc((size_t)DFFN * DMODEL * 2);
  bf16_t* wF2 = (bf16_t*)alloc((size_t)DFFN * DMODEL * 2);

  const long PSTR = (long)MROWS * DMODEL;

  // ts: 128 -> gemm128; 256 -> gemm256
  auto gemm = [&](int ts, const bf16_t* A, const bf16_t* Bm, const float* bias,
                  const float* resid, float* oF, bf16_t* oB, int M, int N, int K,
                  int lda, int ldb, int ldc, int act, int ksplit) {
    GP p{A, Bm, bias, resid, oF, oB, M, N, K, lda, ldb, ldc, PSTR, act, ksplit};
    if (ts == 256) {
      dim3 g((unsigned)(M / 256), (unsigned)(N / 256), (unsigned)ksplit);
      gemm256<<<g, 512, 0, stream>>>(p);
    } else {
      dim3 g((unsigned)(M / 128), (unsigned)(N / 128), (unsigned)ksplit);
      gemm128<<<g, 256, 0, stream>>>(p);
    }
  };

  const long WSZ = (long)DMODEL * DMODEL;

  emb_kernel<<<MROWS, 256, 0, stream>>>(tgt, embt, res);
  cvt_kernel<<<(MROWS * DMODEL / 4 + 255) / 256, 256, 0, stream>>>(memb, membb,
                                                                   MROWS * DMODEL / 4);
  // ln1 output lives in ctxb (QKV input); xb stays dead across FFN2's aliased partials
  ln_kernel<<<MROWS, 256, 0, stream>>>(res, ln_g, ln_b, ctxb, nullptr);

  for (int l = 0; l < NLAYER; ++l) {
    const float* saw = sa_w + (long)l * 4 * WSZ;
    const float* sab = sa_b + (long)l * 4 * DMODEL;
    const float* caw = ca_w + (long)l * 4 * WSZ;
    const float* cab = ca_b + (long)l * 4 * DMODEL;

    // ======== self-attention ========   (ctxb = ln1(res))
    cvt_kernel<<<(int)((WSZ + 255) / 256), 256, 0, stream>>>(saw, wA, (int)WSZ);
    gemm(256, ctxb, wA, sab, nullptr, nullptr, qkvb, MROWS, 3 * DMODEL, DMODEL,
         DMODEL, DMODEL, 3 * DMODEL, 0, 1);
    attn_kernel<<<dim3(SEQ / QT, BATCH * NHEAD), 256, 0, stream>>>(qkvb, tgt, ctxb, 1);
    gemm(128, ctxb, wA + 3 * WSZ, nullptr, nullptr, parts, nullptr, MROWS, DMODEL,
         DMODEL, DMODEL, DMODEL, DMODEL, 0, 2);
    reduce_ln_kernel<<<MROWS, 256, 0, stream>>>(parts, PSTR, 2, sab + 3 * DMODEL, res,
                                                ln_g + (l * 3 + 1) * DMODEL,
                                                ln_b + (l * 3 + 1) * DMODEL, xb, nullptr);

    // ======== cross-attention ========  (xb = ln2)
    cvt_kernel<<<(int)((WSZ + 255) / 256), 256, 0, stream>>>(caw, wA, (int)WSZ);
    gemm(128, xb, wA, nullptr, nullptr, parts, nullptr, MROWS, DMODEL, DMODEL,
         DMODEL, DMODEL, DMODEL, 0, 2);
    reduce_cvtq_kernel<<<MROWS, 256, 0, stream>>>(parts, PSTR, 2, cab, qkvb);
    gemm(128, membb, wA + WSZ, cab + DMODEL, nullptr, nullptr, qkvb + DMODEL, MROWS,
         2 * DMODEL, DMODEL, DMODEL, DMODEL, 3 * DMODEL, 0, 1);
    attn_kernel<<<dim3(SEQ / QT, BATCH * NHEAD), 256, 0, stream>>>(qkvb, srct, ctxb, 0);
    gemm(128, ctxb, wA + 3 * WSZ, nullptr, nullptr, parts, nullptr, MROWS, DMODEL,
         DMODEL, DMODEL, DMODEL, DMODEL, 0, 2);
    reduce_ln_kernel<<<MROWS, 256, 0, stream>>>(parts, PSTR, 2, cab + 3 * DMODEL, res,
                                                ln_g + (l * 3 + 2) * DMODEL,
                                                ln_b + (l * 3 + 2) * DMODEL, xb, nullptr);

    // ======== FFN ========  (xb = ln3)
    cvt_kernel<<<(int)((DFFN * (long)DMODEL / 4 + 255) / 256), 256, 0, stream>>>(
        ff_w1 + (long)l * DFFN * DMODEL, wF1, (int)(DFFN * (long)DMODEL / 4));
    cvt_kernel<<<(int)((DFFN * (long)DMODEL / 4 + 255) / 256), 256, 0, stream>>>(
        ff_w2 + (long)l * DFFN * DMODEL, wF2, (int)(DFFN * (long)DMODEL / 4));
    gemm(256, xb, wF1, ff_b1 + (long)l * DFFN, nullptr, nullptr, ffh, MROWS, DFFN,
         DMODEL, DMODEL, DMODEL, DFFN, 1, 1);
    // ksplit=4: partials 2,3 alias xb/qkvb (dead here); reduce writes ln1 -> ctxb
    gemm(256, ffh, wF2, nullptr, nullptr, parts, nullptr, MROWS, DMODEL, DFFN,
         DFFN, DFFN, DMODEL, 0, 4);
    if (l < NLAYER - 1) {
      reduce_ln_kernel<<<MROWS, 256, 0, stream>>>(parts, PSTR, 4, ff_b2 + (long)l * DMODEL,
                                                  res, ln_g + ((l + 1) * 3) * DMODEL,
                                                  ln_b + ((l + 1) * 3) * DMODEL, ctxb, nullptr);
    } else {
      reduce_ln_kernel<<<MROWS, 256, 0, stream>>>(parts, PSTR, 4, ff_b2 + (long)l * DMODEL,
                                                  res, out_g, out_b, nullptr, out);
    }
  }
}

// Round 5
// 2087.602 us; speedup vs baseline: 1.4429x; 1.4429x over previous
//
#include <hip/hip_runtime.h>
#include <math.h>
#include <stdint.h>

typedef __bf16 bf16_t;
typedef __bf16 bf16x8 __attribute__((ext_vector_type(8)));
typedef __bf16 bf16x4 __attribute__((ext_vector_type(4)));
typedef float f32x4 __attribute__((ext_vector_type(4)));

#define NLAYER 6
#define DMODEL 768
#define NHEAD 12
#define DHEAD 64
#define SEQ 512
#define BATCH 8
#define MROWS 4096 /* BATCH*SEQ */
#define DFFN 3072

// ---------- helpers ----------

__device__ inline void async_load16(const void* g, void* lds) {
  const __attribute__((address_space(1))) void* gp =
      (const __attribute__((address_space(1))) void*)(uintptr_t)g;
  __attribute__((address_space(3))) void* lp =
      (__attribute__((address_space(3))) void*)(uint32_t)(uintptr_t)lds;
  __builtin_amdgcn_global_load_lds(gp, lp, 16, 0, 0);
}

#define LGKM0 __builtin_amdgcn_s_waitcnt(0xC07F) /* lgkmcnt(0) only */

__device__ inline float wsum(float v) {
#pragma unroll
  for (int o = 32; o > 0; o >>= 1) v += __shfl_xor(v, o, 64);
  return v;
}

__device__ inline float gelu_f(float x) {
  float u = 0.7978845608028654f * (x + 0.044715f * x * x * x);
  return 0.5f * x * (1.0f + tanhf(u));
}

struct GP {
  const bf16_t* A;
  const bf16_t* B;
  const float* bias;   // [N] or null (ignored when ksplit>1)
  float* outF;         // f32 out (partial base when ksplit>1)
  bf16_t* outB;        // bf16 out or null
  int M, N, K;
  int lda, ldb, ldc;
  long pstride;  // partial-buffer stride (elements) for ksplit>1
  int act;       // 1 = gelu
  int ksplit;
};

// ---------- 128x128 GEMM ----------
// Main loop = round-0 proven structure (BK=32, dbuf, stage-then-vmcnt(4)).
// NEW: LDS-bounce epilogue. f32 partials leave as 256B-contiguous dwordx4
// rows (was 64B scalar runs); bf16 outputs as 128B-contiguous bf16x8 rows
// (was 32B scalar-2B runs). Per-wave private 4.6KB bounce region overlaid
// on the (dead) staging buffers; no cross-wave sharing -> no barrier.
__global__ __launch_bounds__(256) void gemm128(GP p) {
  __shared__ __align__(16) char smem[32768];
  bf16_t* As = (bf16_t*)smem;            // [2][128*32]
  bf16_t* Bs = (bf16_t*)(smem + 16384);  // [2][128*32]
  const int tid = threadIdx.x;
  const int wave = tid >> 6, lane = tid & 63;
  const int wr = wave >> 1, wc = wave & 1;
  const int lrow = lane & 15, kq = lane >> 4;
  const int sr = tid >> 2;
  const int sc = (tid & 3) << 3;
  const int m0 = blockIdx.x * 128;
  const int n0 = blockIdx.y * 128;
  const int zs = (int)blockIdx.z;

  const int kc = p.K / p.ksplit;
  const int kstart = zs * kc;
  const int kend = kstart + kc;

  auto stage = [&](int k0, int buf) {
#pragma unroll
    for (int r = 0; r < 2; ++r)
      async_load16(p.A + (long)(m0 + r * 64 + sr) * p.lda + (k0 + sc),
                   As + buf * 4096 + (r * 64 + wave * 16) * 32);
#pragma unroll
    for (int r = 0; r < 2; ++r)
      async_load16(p.B + (long)(n0 + r * 64 + sr) * p.ldb + (k0 + sc),
                   Bs + buf * 4096 + (r * 64 + wave * 16) * 32);
  };

  f32x4 acc[4][4] = {};
  stage(kstart, 0);
  int cur = 0;

  for (int k0 = kstart; k0 < kend; k0 += 32) {
    const bool hn = (k0 + 32) < kend;
    if (hn) {
      stage(k0 + 32, cur ^ 1);
      __builtin_amdgcn_s_waitcnt(0xF74);  // vmcnt(4): cur buf's 4 loads done
    } else {
      __builtin_amdgcn_s_waitcnt(0xF70);  // vmcnt(0)
    }
    __builtin_amdgcn_s_barrier();

    bf16x8 af[4], bfr[4];
#pragma unroll
    for (int i = 0; i < 4; ++i)
      af[i] = *(const bf16x8*)&As[cur * 4096 + (wr * 64 + i * 16 + lrow) * 32 + kq * 8];
#pragma unroll
    for (int j = 0; j < 4; ++j)
      bfr[j] = *(const bf16x8*)&Bs[cur * 4096 + (wc * 64 + j * 16 + lrow) * 32 + kq * 8];
#pragma unroll
    for (int i = 0; i < 4; ++i)
#pragma unroll
      for (int j = 0; j < 4; ++j)
        acc[i][j] = __builtin_amdgcn_mfma_f32_16x16x32_bf16(af[i], bfr[j], acc[i][j], 0, 0, 0);

    __builtin_amdgcn_s_barrier();  // all waves done reading cur before overwrite
    cur ^= 1;
  }

  // ---- epilogue: LDS-bounce coalesced stores ----
  const int colbase = n0 + wc * 64;
  const int lc = lrow;  // lane & 15
  float* eb = (float*)(smem + wave * 4608);  // per-wave 4.6KB, staging is dead

  if (p.ksplit > 1) {
    float* po = p.outF + (long)zs * p.pstride;
#pragma unroll
    for (int i = 0; i < 4; ++i) {
      const int rg0 = m0 + wr * 64 + i * 16;
#pragma unroll
      for (int j = 0; j < 4; ++j)
#pragma unroll
        for (int r = 0; r < 4; ++r)
          eb[(kq * 4 + r) * 68 + j * 16 + lc] = acc[i][j][r];
      LGKM0;
#pragma unroll
      for (int q = 0; q < 4; ++q) {
        const int row = q * 4 + kq;
        const f32x4 v = *(const f32x4*)&eb[row * 68 + lc * 4];
        *(f32x4*)&po[(long)(rg0 + row) * p.ldc + colbase + lc * 4] = v;
      }
      LGKM0;  // reads retired before next i overwrites
    }
  } else {
    float bs[4] = {0.f, 0.f, 0.f, 0.f};
    if (p.bias) {
#pragma unroll
      for (int j = 0; j < 4; ++j) bs[j] = p.bias[colbase + j * 16 + lc];
    }
    bf16_t* bh = (bf16_t*)eb;  // stride 72 (144B = 9x16B, quad-rotating)
    const int l8r = lane >> 3, l8c = lane & 7;
#pragma unroll
    for (int i = 0; i < 4; ++i) {
      const int rg0 = m0 + wr * 64 + i * 16;
#pragma unroll
      for (int j = 0; j < 4; ++j)
#pragma unroll
        for (int r = 0; r < 4; ++r) {
          float y = acc[i][j][r] + bs[j];
          if (p.act) y = gelu_f(y);
          bh[(kq * 4 + r) * 72 + j * 16 + lc] = (bf16_t)y;
        }
      LGKM0;
      if (p.outB) {
#pragma unroll
        for (int q = 0; q < 2; ++q) {
          const int row = q * 8 + l8r;
          const bf16x8 v = *(const bf16x8*)&bh[row * 72 + l8c * 8];
          *(bf16x8*)&p.outB[(long)(rg0 + row) * p.ldc + colbase + l8c * 8] = v;
        }
      }
      if (p.outF) {  // unused path, kept for safety
#pragma unroll
        for (int j = 0; j < 4; ++j)
#pragma unroll
          for (int r = 0; r < 4; ++r) {
            float y = acc[i][j][r] + bs[j];
            if (p.act) y = gelu_f(y);
            p.outF[(long)(rg0 + kq * 4 + r) * p.ldc + colbase + j * 16 + lc] = y;
          }
      }
      LGKM0;
    }
  }
}

// ---------- fused flash attention ----------
#define QT 64
#define KT 128
#define VPAD 136

__global__ __launch_bounds__(256) void attn_kernel(const bf16_t* __restrict__ qkv,
                                                   const int* __restrict__ toks,
                                                   bf16_t* __restrict__ ctx, int causal) {
  __shared__ __align__(16) bf16_t Qs[QT * 64];
  __shared__ __align__(16) bf16_t Ks[KT * 64];
  __shared__ __align__(16) bf16_t Vs[64 * VPAD];
  __shared__ __align__(16) bf16_t Ps[QT * VPAD];
  __shared__ int Ts[SEQ];
  const int tid = threadIdx.x;
  const int wave = tid >> 6, lane = tid & 63;
  const int lm = lane & 15, lq = lane >> 4;
  const int q0 = blockIdx.x * QT;
  const int bh = blockIdx.y;
  const int b = bh / NHEAD, h = bh % NHEAD;
  const long rowbase = (long)b * SEQ;
  const int LD = 3 * DMODEL;
  const bf16_t* Qg = qkv + (rowbase + q0) * LD + h * DHEAD;
  const bf16_t* Kg = qkv + rowbase * LD + DMODEL + h * DHEAD;
  const bf16_t* Vg = qkv + rowbase * LD + 2 * DMODEL + h * DHEAD;

  Ts[tid] = toks[b * SEQ + tid];
  Ts[tid + 256] = toks[b * SEQ + tid + 256];

#pragma unroll
  for (int r = 0; r < 2; ++r) {
    const int c = r * 256 + tid;
    const int row = c >> 3, c8 = (c & 7) * 8;
    async_load16(Qg + (long)row * LD + c8, &Qs[c * 8]);
  }
  __syncthreads();

  bf16x8 aQ0 = *(const bf16x8*)&Qs[(wave * 16 + lm) * 64 + lq * 8];
  bf16x8 aQ1 = *(const bf16x8*)&Qs[(wave * 16 + lm) * 64 + 32 + lq * 8];

  float m_i[4], l_i[4];
  f32x4 O[4] = {};
#pragma unroll
  for (int r = 0; r < 4; ++r) { m_i[r] = -3.0e38f; l_i[r] = 0.0f; }

  const int s_end = causal ? (q0 + QT) : SEQ;
  for (int s0 = 0; s0 < s_end; s0 += KT) {
    __syncthreads();
#pragma unroll
    for (int r = 0; r < 4; ++r) {
      const int c = r * 256 + tid;
      const int row = c >> 3, c8 = (c & 7) * 8;
      async_load16(Kg + (long)(s0 + row) * LD + c8, &Ks[c * 8]);
    }
#pragma unroll
    for (int r = 0; r < 4; ++r) {
      const int c = r * 256 + tid;
      const int row = c >> 3, c8 = (c & 7) * 8;
      const bf16x8 vv = *(const bf16x8*)(Vg + (long)(s0 + row) * LD + c8);
#pragma unroll
      for (int j = 0; j < 8; ++j) Vs[(c8 + j) * VPAD + row] = vv[j];
    }
    __syncthreads();

    f32x4 sv[8];
#pragma unroll
    for (int jt = 0; jt < 8; ++jt) {
      const bf16x8 b0 = *(const bf16x8*)&Ks[(jt * 16 + lm) * 64 + lq * 8];
      const bf16x8 b1 = *(const bf16x8*)&Ks[(jt * 16 + lm) * 64 + 32 + lq * 8];
      f32x4 a = {};
      a = __builtin_amdgcn_mfma_f32_16x16x32_bf16(aQ0, b0, a, 0, 0, 0);
      a = __builtin_amdgcn_mfma_f32_16x16x32_bf16(aQ1, b1, a, 0, 0, 0);
      sv[jt] = a;
    }

#pragma unroll
    for (int r = 0; r < 4; ++r) {
      const int qa = q0 + wave * 16 + lq * 4 + r;
      float sr[8];
      float mx = -3.0e38f;
#pragma unroll
      for (int jt = 0; jt < 8; ++jt) {
        const int k = s0 + jt * 16 + lm;
        const float x = sv[jt][r] * 0.125f;
        const bool msk = (Ts[k] == 0) || (causal && (k > qa));
        sr[jt] = msk ? -1.0e18f : x;
        mx = fmaxf(mx, sr[jt]);
      }
#pragma unroll
      for (int o = 1; o < 16; o <<= 1) mx = fmaxf(mx, __shfl_xor(mx, o, 64));
      const float mn = fmaxf(m_i[r], mx);
      const float alpha = __expf(m_i[r] - mn);
      float sum = 0.0f;
#pragma unroll
      for (int jt = 0; jt < 8; ++jt) {
        const float pv = __expf(sr[jt] - mn);
        sr[jt] = pv;
        sum += pv;
      }
#pragma unroll
      for (int o = 1; o < 16; o <<= 1) sum += __shfl_xor(sum, o, 64);
      l_i[r] = l_i[r] * alpha + sum;
      m_i[r] = mn;
#pragma unroll
      for (int jn = 0; jn < 4; ++jn) O[jn][r] *= alpha;
#pragma unroll
      for (int jt = 0; jt < 8; ++jt)
        Ps[(wave * 16 + lq * 4 + r) * VPAD + jt * 16 + lm] = (bf16_t)sr[jt];
    }

#pragma unroll
    for (int kt = 0; kt < 4; ++kt) {
      const bf16x8 aP = *(const bf16x8*)&Ps[(wave * 16 + lm) * VPAD + kt * 32 + lq * 8];
#pragma unroll
      for (int jn = 0; jn < 4; ++jn) {
        const bf16x8 bV = *(const bf16x8*)&Vs[(jn * 16 + lm) * VPAD + kt * 32 + lq * 8];
        O[jn] = __builtin_amdgcn_mfma_f32_16x16x32_bf16(aP, bV, O[jn], 0, 0, 0);
      }
    }
  }

#pragma unroll
  for (int r = 0; r < 4; ++r) {
    const int q = q0 + wave * 16 + lq * 4 + r;
    const float inv = 1.0f / l_i[r];
#pragma unroll
    for (int jn = 0; jn < 4; ++jn) {
      const int d = jn * 16 + lm;
      ctx[(rowbase + q) * DMODEL + h * DHEAD + d] = (bf16_t)(O[jn][r] * inv);
    }
  }
}

// ---------- LayerNorm (row = 768) ----------
__global__ __launch_bounds__(256) void ln_kernel(const float* __restrict__ X,
                                                 const float* __restrict__ g,
                                                 const float* __restrict__ b,
                                                 bf16_t* __restrict__ outB,
                                                 float* __restrict__ outF) {
  const int row = blockIdx.x, tid = threadIdx.x;
  const float* xr = X + (long)row * DMODEL;
  const float v0 = xr[tid], v1 = xr[tid + 256], v2 = xr[tid + 512];
  __shared__ float r1[4], r2[4];
  const int wv = tid >> 6, ln = tid & 63;
  float s = wsum(v0 + v1 + v2);
  if (ln == 0) r1[wv] = s;
  __syncthreads();
  const float mean = (r1[0] + r1[1] + r1[2] + r1[3]) * (1.0f / DMODEL);
  const float d0 = v0 - mean, d1 = v1 - mean, d2 = v2 - mean;
  float q = wsum(d0 * d0 + d1 * d1 + d2 * d2);
  if (ln == 0) r2[wv] = q;
  __syncthreads();
  const float var = (r2[0] + r2[1] + r2[2] + r2[3]) * (1.0f / DMODEL);
  const float rs = rsqrtf(var + 1e-6f);
  const float y0 = d0 * rs * g[tid] + b[tid];
  const float y1 = d1 * rs * g[tid + 256] + b[tid + 256];
  const float y2 = d2 * rs * g[tid + 512] + b[tid + 512];
  const long base = (long)row * DMODEL;
  if (outB) {
    outB[base + tid] = (bf16_t)y0;
    outB[base + tid + 256] = (bf16_t)y1;
    outB[base + tid + 512] = (bf16_t)y2;
  }
  if (outF) {
    outF[base + tid] = y0;
    outF[base + tid + 256] = y1;
    outF[base + tid + 512] = y2;
  }
}

// ---------- reduce split-K partials + bias + residual, then LayerNorm ----------
__global__ __launch_bounds__(256) void reduce_ln_kernel(
    const float* __restrict__ parts, long pstr, int np,
    const float* __restrict__ bias, float* __restrict__ res,
    const float* __restrict__ g, const float* __restrict__ b,
    bf16_t* __restrict__ outB, float* __restrict__ outF) {
  const int row = blockIdx.x, tid = threadIdx.x;
  const long base = (long)row * DMODEL;
  float v0, v1, v2;
  {
    float t0 = res[base + tid] + bias[tid];
    float t1 = res[base + tid + 256] + bias[tid + 256];
    float t2 = res[base + tid + 512] + bias[tid + 512];
    for (int p = 0; p < np; ++p) {
      const float* pp = parts + p * pstr + base;
      t0 += pp[tid];
      t1 += pp[tid + 256];
      t2 += pp[tid + 512];
    }
    v0 = t0; v1 = t1; v2 = t2;
    res[base + tid] = t0;
    res[base + tid + 256] = t1;
    res[base + tid + 512] = t2;
  }
  __shared__ float r1[4], r2[4];
  const int wv = tid >> 6, ln = tid & 63;
  float s = wsum(v0 + v1 + v2);
  if (ln == 0) r1[wv] = s;
  __syncthreads();
  const float mean = (r1[0] + r1[1] + r1[2] + r1[3]) * (1.0f / DMODEL);
  const float d0 = v0 - mean, d1 = v1 - mean, d2 = v2 - mean;
  float q = wsum(d0 * d0 + d1 * d1 + d2 * d2);
  if (ln == 0) r2[wv] = q;
  __syncthreads();
  const float var = (r2[0] + r2[1] + r2[2] + r2[3]) * (1.0f / DMODEL);
  const float rs = rsqrtf(var + 1e-6f);
  const float y0 = d0 * rs * g[tid] + b[tid];
  const float y1 = d1 * rs * g[tid + 256] + b[tid + 256];
  const float y2 = d2 * rs * g[tid + 512] + b[tid + 512];
  if (outB) {
    outB[base + tid] = (bf16_t)y0;
    outB[base + tid + 256] = (bf16_t)y1;
    outB[base + tid + 512] = (bf16_t)y2;
  }
  if (outF) {
    outF[base + tid] = y0;
    outF[base + tid + 256] = y1;
    outF[base + tid + 512] = y2;
  }
}

// ---------- reduce split-K partials + bias -> strided bf16 (CA-q into qkv) ----------
__global__ __launch_bounds__(256) void reduce_cvtq_kernel(
    const float* __restrict__ parts, long pstr, int np,
    const float* __restrict__ bias, bf16_t* __restrict__ o) {
  const int row = blockIdx.x, tid = threadIdx.x;
  const long base = (long)row * DMODEL;
  const long ob = (long)row * 3 * DMODEL;
#pragma unroll
  for (int c = 0; c < 3; ++c) {
    const int col = tid + c * 256;
    float t = bias[col];
    for (int p = 0; p < np; ++p) t += parts[p * pstr + base + col];
    o[ob + col] = (bf16_t)t;
  }
}

// ---------- embedding * sqrt(D) + sinusoidal PE ----------
__global__ __launch_bounds__(256) void emb_kernel(const int* __restrict__ tgt,
                                                  const float* __restrict__ tab,
                                                  float* __restrict__ res) {
  const int row = blockIdx.x;
  const int t = row & (SEQ - 1);
  const long tok = tgt[row];
  const float* er = tab + tok * DMODEL;
  float* orow = res + (long)row * DMODEL;
  const float c1 = -9.210340371976184f / 768.0f;
  for (int c = threadIdx.x; c < DMODEL; c += 256) {
    const float e = er[c] * 27.712812921102035f;
    const float div = expf((float)(c & ~1) * c1);
    const float ang = (float)t * div;
    const float pe = (c & 1) ? cosf(ang) : sinf(ang);
    orow[c] = e + pe;
  }
}

// ---------- f32 -> bf16 convert (n4 = n/4) ----------
__global__ __launch_bounds__(256) void cvt_kernel(const float* __restrict__ in,
                                                  bf16_t* __restrict__ o, int n4) {
  const int i = blockIdx.x * 256 + threadIdx.x;
  if (i < n4) {
    const float4 v = ((const float4*)in)[i];
    bf16x4 r = {(bf16_t)v.x, (bf16_t)v.y, (bf16_t)v.z, (bf16_t)v.w};
    ((bf16x4*)o)[i] = r;
  }
}

// ---------- host ----------
extern "C" void kernel_launch(void* const* d_in, const int* in_sizes, int n_in,
                              void* d_out, int out_size, void* d_ws, size_t ws_size,
                              hipStream_t stream) {
  (void)in_sizes; (void)n_in; (void)out_size; (void)ws_size;
  const int* tgt = (const int*)d_in[0];
  const int* srct = (const int*)d_in[1];
  const float* memb = (const float*)d_in[2];
  const float* embt = (const float*)d_in[3];
  const float* sa_w = (const float*)d_in[4];
  const float* sa_b = (const float*)d_in[5];
  const float* ca_w = (const float*)d_in[6];
  const float* ca_b = (const float*)d_in[7];
  const float* ln_g = (const float*)d_in[8];
  const float* ln_b = (const float*)d_in[9];
  const float* ff_w1 = (const float*)d_in[10];
  const float* ff_b1 = (const float*)d_in[11];
  const float* ff_w2 = (const float*)d_in[12];
  const float* ff_b2 = (const float*)d_in[13];
  const float* out_g = (const float*)d_in[14];
  const float* out_b = (const float*)d_in[15];
  float* out = (float*)d_out;

  char* wsb = (char*)d_ws;
  size_t off = 0;
  auto alloc = [&](size_t bytes) -> void* {
    void* pp = wsb + off;
    off = (off + bytes + 255) & ~(size_t)255;
    return pp;
  };
  // Allocation ORDER/SIZES load-bearing: ksplit=4 partials span
  // parts(2*PSTR) + xb + qkvb exactly (xb+qkvb are DEAD at every ksplit=4
  // GEMM: all LN outputs now live in ctxb, never xb).
  float* res = (float*)alloc((size_t)MROWS * DMODEL * 4);
  float* parts = (float*)alloc((size_t)2 * MROWS * DMODEL * 4);  // partials 0..1
  bf16_t* xb = (bf16_t*)alloc((size_t)MROWS * DMODEL * 2);       // partial 2 space
  bf16_t* qkvb = (bf16_t*)alloc((size_t)MROWS * 3 * DMODEL * 2); // partial 2/3 space
  bf16_t* ctxb = (bf16_t*)alloc((size_t)MROWS * DMODEL * 2);
  bf16_t* membb = (bf16_t*)alloc((size_t)MROWS * DMODEL * 2);
  bf16_t* ffh = (bf16_t*)alloc((size_t)MROWS * DFFN * 2);
  bf16_t* wA = (bf16_t*)alloc((size_t)4 * DMODEL * DMODEL * 2);
  bf16_t* wF1 = (bf16_t*)alloc((size_t)DFFN * DMODEL * 2);
  bf16_t* wF2 = (bf16_t*)alloc((size_t)DFFN * DMODEL * 2);
  (void)xb;

  const long PSTR = (long)MROWS * DMODEL;

  auto gemm = [&](const bf16_t* A, const bf16_t* Bm, const float* bias,
                  float* oF, bf16_t* oB, int M, int N, int K,
                  int lda, int ldb, int ldc, int act, int ksplit) {
    GP p{A, Bm, bias, oF, oB, M, N, K, lda, ldb, ldc, PSTR, act, ksplit};
    dim3 g((unsigned)(M / 128), (unsigned)(N / 128), (unsigned)ksplit);
    gemm128<<<g, 256, 0, stream>>>(p);
  };

  const long WSZ = (long)DMODEL * DMODEL;

  emb_kernel<<<MROWS, 256, 0, stream>>>(tgt, embt, res);
  cvt_kernel<<<(MROWS * DMODEL / 4 + 255) / 256, 256, 0, stream>>>(memb, membb,
                                                                   MROWS * DMODEL / 4);
  ln_kernel<<<MROWS, 256, 0, stream>>>(res, ln_g, ln_b, ctxb, nullptr);

  for (int l = 0; l < NLAYER; ++l) {
    const float* saw = sa_w + (long)l * 4 * WSZ;
    const float* sab = sa_b + (long)l * 4 * DMODEL;
    const float* caw = ca_w + (long)l * 4 * WSZ;
    const float* cab = ca_b + (long)l * 4 * DMODEL;

    // ======== self-attention ========   (ctxb = ln1)
    cvt_kernel<<<(int)((WSZ + 255) / 256), 256, 0, stream>>>(saw, wA, (int)WSZ);
    gemm(ctxb, wA, sab, nullptr, qkvb, MROWS, 3 * DMODEL, DMODEL,
         DMODEL, DMODEL, 3 * DMODEL, 0, 1);
    attn_kernel<<<dim3(SEQ / QT, BATCH * NHEAD), 256, 0, stream>>>(qkvb, tgt, ctxb, 1);
    // SA-out: ksplit=4 (xb/qkvb dead -> partials 2,3 alias them)
    gemm(ctxb, wA + 3 * WSZ, nullptr, parts, nullptr, MROWS, DMODEL, DMODEL,
         DMODEL, DMODEL, DMODEL, 0, 4);
    reduce_ln_kernel<<<MROWS, 256, 0, stream>>>(parts, PSTR, 4, sab + 3 * DMODEL, res,
                                                ln_g + (l * 3 + 1) * DMODEL,
                                                ln_b + (l * 3 + 1) * DMODEL, ctxb, nullptr);

    // ======== cross-attention ========  (ctxb = ln2)
    cvt_kernel<<<(int)((WSZ + 255) / 256), 256, 0, stream>>>(caw, wA, (int)WSZ);
    // CA-q stays ksplit=2 (its reduce writes qkvb, which aliases partials 2,3)
    gemm(ctxb, wA, nullptr, parts, nullptr, MROWS, DMODEL, DMODEL,
         DMODEL, DMODEL, DMODEL, 0, 2);
    reduce_cvtq_kernel<<<MROWS, 256, 0, stream>>>(parts, PSTR, 2, cab, qkvb);
    gemm(membb, wA + WSZ, cab + DMODEL, nullptr, qkvb + DMODEL, MROWS,
         2 * DMODEL, DMODEL, DMODEL, DMODEL, 3 * DMODEL, 0, 1);
    attn_kernel<<<dim3(SEQ / QT, BATCH * NHEAD), 256, 0, stream>>>(qkvb, srct, ctxb, 0);
    // CA-out: ksplit=4 (xb/qkvb dead again)
    gemm(ctxb, wA + 3 * WSZ, nullptr, parts, nullptr, MROWS, DMODEL, DMODEL,
         DMODEL, DMODEL, DMODEL, 0, 4);
    reduce_ln_kernel<<<MROWS, 256, 0, stream>>>(parts, PSTR, 4, cab + 3 * DMODEL, res,
                                                ln_g + (l * 3 + 2) * DMODEL,
                                                ln_b + (l * 3 + 2) * DMODEL, ctxb, nullptr);

    // ======== FFN ========  (ctxb = ln3)
    cvt_kernel<<<(int)((DFFN * (long)DMODEL / 4 + 255) / 256), 256, 0, stream>>>(
        ff_w1 + (long)l * DFFN * DMODEL, wF1, (int)(DFFN * (long)DMODEL / 4));
    cvt_kernel<<<(int)((DFFN * (long)DMODEL / 4 + 255) / 256), 256, 0, stream>>>(
        ff_w2 + (long)l * DFFN * DMODEL, wF2, (int)(DFFN * (long)DMODEL / 4));
    gemm(ctxb, wF1, ff_b1 + (long)l * DFFN, nullptr, ffh, MROWS, DFFN,
         DMODEL, DMODEL, DMODEL, DFFN, 1, 1);
    gemm(ffh, wF2, nullptr, parts, nullptr, MROWS, DMODEL, DFFN,
         DFFN, DFFN, DMODEL, 0, 4);
    if (l < NLAYER - 1) {
      reduce_ln_kernel<<<MROWS, 256, 0, stream>>>(parts, PSTR, 4, ff_b2 + (long)l * DMODEL,
                                                  res, ln_g + ((l + 1) * 3) * DMODEL,
                                                  ln_b + ((l + 1) * 3) * DMODEL, ctxb, nullptr);
    } else {
      reduce_ln_kernel<<<MROWS, 256, 0, stream>>>(parts, PSTR, 4, ff_b2 + (long)l * DMODEL,
                                                  res, out_g, out_b, nullptr, out);
    }
  }
}

// Round 6
// 2058.245 us; speedup vs baseline: 1.4635x; 1.0143x over previous
//
#include <hip/hip_runtime.h>
#include <math.h>
#include <stdint.h>

typedef __bf16 bf16_t;
typedef __bf16 bf16x8 __attribute__((ext_vector_type(8)));
typedef __bf16 bf16x4 __attribute__((ext_vector_type(4)));
typedef float f32x4 __attribute__((ext_vector_type(4)));

#define NLAYER 6
#define DMODEL 768
#define NHEAD 12
#define DHEAD 64
#define SEQ 512
#define BATCH 8
#define MROWS 4096 /* BATCH*SEQ */
#define DFFN 3072

// ---------- helpers ----------

__device__ inline void async_load16(const void* g, void* lds) {
  const __attribute__((address_space(1))) void* gp =
      (const __attribute__((address_space(1))) void*)(uintptr_t)g;
  __attribute__((address_space(3))) void* lp =
      (__attribute__((address_space(3))) void*)(uint32_t)(uintptr_t)lds;
  __builtin_amdgcn_global_load_lds(gp, lp, 16, 0, 0);
}

#define VMCNT(n) __builtin_amdgcn_s_waitcnt(0x0F70 | (n))
#define LGKM0 __builtin_amdgcn_s_waitcnt(0xC07F) /* lgkmcnt(0) only */

__device__ inline float wsum(float v) {
#pragma unroll
  for (int o = 32; o > 0; o >>= 1) v += __shfl_xor(v, o, 64);
  return v;
}

__device__ inline float gelu_f(float x) {
  // 0.5x(1+tanh(u)) == x / (1 + exp(-2u)); hardware v_exp_f32 path
  const float u = x + 0.044715f * x * x * x;
  return x / (1.0f + __expf(-1.5957691216057308f * u));
}

struct GP {
  const bf16_t* A;
  const bf16_t* B;
  const float* bias;   // [N] or null (ignored when ksplit>1)
  float* outF;         // f32 out (partial base when ksplit>1)
  bf16_t* outB;        // bf16 out or null
  int M, N, K;
  int lda, ldb, ldc;
  long pstride;  // partial-buffer stride (elements) for ksplit>1
  int act;       // 1 = gelu
  int ksplit;
};

// ---------- 128x128 GEMM ----------
// Round-0 proven loop shape, upgraded:
//  * TRIPLE-buffered staging (48KB LDS, 3 blocks/CU): vmcnt(8) waits only on
//    loads issued TWO K-steps ago (2x latency slack vs round-0's one step).
//  * Conflict-free LDS swizzle (HW-verified on the r1/r2 256-tile kernels:
//    BANK_CONFLICT == 0): data slot s of row r stored at slot s^((r>>1)&3);
//    staged via inverse-swizzled global source column (both-sides rule),
//    read at kq^((lrow>>1)&3). Kills the 2.46M conflicts/dispatch of r5.
//  * LDS-bounce coalesced epilogue (r5, proven: WRITE_SIZE == ideal).
__global__ __launch_bounds__(256) void gemm128(GP p) {
  __shared__ __align__(16) char smem[49152];
  bf16_t* As = (bf16_t*)smem;            // [3][128*32]
  bf16_t* Bs = (bf16_t*)(smem + 24576);  // [3][128*32]
  const int tid = threadIdx.x;
  const int wave = tid >> 6, lane = tid & 63;
  const int wr = wave >> 1, wc = wave & 1;
  const int lrow = lane & 15, kq = lane >> 4;
  const int swz = (kq ^ ((lrow >> 1) & 3)) * 8;  // read slot (elements)
  const int sr = tid >> 2;
  // stage: lane covers row base+(l>>2), writes LDS slot l&3 (linear dest);
  // source data slot = (l&3) ^ ((l>>3)&3)  (inverse swizzle; wave-safe since
  // (tid>>3)&3 == ((lane)>>3)&3 for 64-lane waves)
  const int scs = ((tid & 3) ^ ((tid >> 3) & 3)) << 3;
  const int m0 = blockIdx.x * 128;
  const int n0 = blockIdx.y * 128;
  const int zs = (int)blockIdx.z;

  const int kc = p.K / p.ksplit;
  const int kstart = zs * kc;
  const int kend = kstart + kc;

  auto stage = [&](int k0, int buf) {
#pragma unroll
    for (int r = 0; r < 2; ++r)
      async_load16(p.A + (long)(m0 + r * 64 + sr) * p.lda + (k0 + scs),
                   As + buf * 4096 + (r * 64 + wave * 16) * 32);
#pragma unroll
    for (int r = 0; r < 2; ++r)
      async_load16(p.B + (long)(n0 + r * 64 + sr) * p.ldb + (k0 + scs),
                   Bs + buf * 4096 + (r * 64 + wave * 16) * 32);
  };

  f32x4 acc[4][4] = {};
  stage(kstart, 0);
  if (kstart + 32 < kend) stage(kstart + 32, 1);
  int cur = 0, nxt = 1, fut = 2;

  for (int k0 = kstart; k0 < kend; k0 += 32) {
    if (k0 + 64 < kend) {
      stage(k0 + 64, fut);  // fut's last readers finished 2 barriers ago
      VMCNT(8);             // cur's 4 loads (issued 2 iters ago) landed
    } else if (k0 + 32 < kend) {
      VMCNT(4);
    } else {
      VMCNT(0);
    }
    __builtin_amdgcn_s_barrier();

    const int cb = cur * 4096;
    bf16x8 af[4], bfr[4];
#pragma unroll
    for (int i = 0; i < 4; ++i)
      af[i] = *(const bf16x8*)&As[cb + (wr * 64 + i * 16 + lrow) * 32 + swz];
#pragma unroll
    for (int j = 0; j < 4; ++j)
      bfr[j] = *(const bf16x8*)&Bs[cb + (wc * 64 + j * 16 + lrow) * 32 + swz];
#pragma unroll
    for (int i = 0; i < 4; ++i)
#pragma unroll
      for (int j = 0; j < 4; ++j)
        acc[i][j] = __builtin_amdgcn_mfma_f32_16x16x32_bf16(af[i], bfr[j], acc[i][j], 0, 0, 0);

    __builtin_amdgcn_s_barrier();  // all waves done reading cur before reuse
    const int t = cur; cur = nxt; nxt = fut; fut = t;
  }

  // ---- epilogue: LDS-bounce coalesced stores (staging LDS is dead) ----
  const int colbase = n0 + wc * 64;
  const int lc = lrow;  // lane & 15
  float* eb = (float*)(smem + wave * 4608);  // per-wave 4.6KB private

  if (p.ksplit > 1) {
    float* po = p.outF + (long)zs * p.pstride;
#pragma unroll
    for (int i = 0; i < 4; ++i) {
      const int rg0 = m0 + wr * 64 + i * 16;
#pragma unroll
      for (int j = 0; j < 4; ++j)
#pragma unroll
        for (int r = 0; r < 4; ++r)
          eb[(kq * 4 + r) * 68 + j * 16 + lc] = acc[i][j][r];
      LGKM0;
#pragma unroll
      for (int q = 0; q < 4; ++q) {
        const int row = q * 4 + kq;
        const f32x4 v = *(const f32x4*)&eb[row * 68 + lc * 4];
        *(f32x4*)&po[(long)(rg0 + row) * p.ldc + colbase + lc * 4] = v;
      }
      LGKM0;  // reads retired before next i overwrites
    }
  } else {
    float bs[4] = {0.f, 0.f, 0.f, 0.f};
    if (p.bias) {
#pragma unroll
      for (int j = 0; j < 4; ++j) bs[j] = p.bias[colbase + j * 16 + lc];
    }
    bf16_t* bh = (bf16_t*)eb;  // stride 72 (144B = 9x16B, quad-rotating)
    const int l8r = lane >> 3, l8c = lane & 7;
#pragma unroll
    for (int i = 0; i < 4; ++i) {
      const int rg0 = m0 + wr * 64 + i * 16;
#pragma unroll
      for (int j = 0; j < 4; ++j)
#pragma unroll
        for (int r = 0; r < 4; ++r) {
          float y = acc[i][j][r] + bs[j];
          if (p.act) y = gelu_f(y);
          bh[(kq * 4 + r) * 72 + j * 16 + lc] = (bf16_t)y;
        }
      LGKM0;
      if (p.outB) {
#pragma unroll
        for (int q = 0; q < 2; ++q) {
          const int row = q * 8 + l8r;
          const bf16x8 v = *(const bf16x8*)&bh[row * 72 + l8c * 8];
          *(bf16x8*)&p.outB[(long)(rg0 + row) * p.ldc + colbase + l8c * 8] = v;
        }
      }
      if (p.outF) {  // unused path, kept for safety
#pragma unroll
        for (int j = 0; j < 4; ++j)
#pragma unroll
          for (int r = 0; r < 4; ++r) {
            float y = acc[i][j][r] + bs[j];
            if (p.act) y = gelu_f(y);
            p.outF[(long)(rg0 + kq * 4 + r) * p.ldc + colbase + j * 16 + lc] = y;
          }
      }
      LGKM0;
    }
  }
}

// ---------- fused flash attention ----------
#define QT 64
#define KT 128
#define VPAD 136

__global__ __launch_bounds__(256) void attn_kernel(const bf16_t* __restrict__ qkv,
                                                   const int* __restrict__ toks,
                                                   bf16_t* __restrict__ ctx, int causal) {
  __shared__ __align__(16) bf16_t Qs[QT * 64];
  __shared__ __align__(16) bf16_t Ks[KT * 64];
  __shared__ __align__(16) bf16_t Vs[64 * VPAD];
  __shared__ __align__(16) bf16_t Ps[QT * VPAD];
  __shared__ int Ts[SEQ];
  const int tid = threadIdx.x;
  const int wave = tid >> 6, lane = tid & 63;
  const int lm = lane & 15, lq = lane >> 4;
  const int q0 = blockIdx.x * QT;
  const int bh = blockIdx.y;
  const int b = bh / NHEAD, h = bh % NHEAD;
  const long rowbase = (long)b * SEQ;
  const int LD = 3 * DMODEL;
  const bf16_t* Qg = qkv + (rowbase + q0) * LD + h * DHEAD;
  const bf16_t* Kg = qkv + rowbase * LD + DMODEL + h * DHEAD;
  const bf16_t* Vg = qkv + rowbase * LD + 2 * DMODEL + h * DHEAD;

  Ts[tid] = toks[b * SEQ + tid];
  Ts[tid + 256] = toks[b * SEQ + tid + 256];

#pragma unroll
  for (int r = 0; r < 2; ++r) {
    const int c = r * 256 + tid;
    const int row = c >> 3, c8 = (c & 7) * 8;
    async_load16(Qg + (long)row * LD + c8, &Qs[c * 8]);
  }
  __syncthreads();

  bf16x8 aQ0 = *(const bf16x8*)&Qs[(wave * 16 + lm) * 64 + lq * 8];
  bf16x8 aQ1 = *(const bf16x8*)&Qs[(wave * 16 + lm) * 64 + 32 + lq * 8];

  float m_i[4], l_i[4];
  f32x4 O[4] = {};
#pragma unroll
  for (int r = 0; r < 4; ++r) { m_i[r] = -3.0e38f; l_i[r] = 0.0f; }

  const int s_end = causal ? (q0 + QT) : SEQ;
  for (int s0 = 0; s0 < s_end; s0 += KT) {
    __syncthreads();
#pragma unroll
    for (int r = 0; r < 4; ++r) {
      const int c = r * 256 + tid;
      const int row = c >> 3, c8 = (c & 7) * 8;
      async_load16(Kg + (long)(s0 + row) * LD + c8, &Ks[c * 8]);
    }
#pragma unroll
    for (int r = 0; r < 4; ++r) {
      const int c = r * 256 + tid;
      const int row = c >> 3, c8 = (c & 7) * 8;
      const bf16x8 vv = *(const bf16x8*)(Vg + (long)(s0 + row) * LD + c8);
#pragma unroll
      for (int j = 0; j < 8; ++j) Vs[(c8 + j) * VPAD + row] = vv[j];
    }
    __syncthreads();

    f32x4 sv[8];
#pragma unroll
    for (int jt = 0; jt < 8; ++jt) {
      const bf16x8 b0 = *(const bf16x8*)&Ks[(jt * 16 + lm) * 64 + lq * 8];
      const bf16x8 b1 = *(const bf16x8*)&Ks[(jt * 16 + lm) * 64 + 32 + lq * 8];
      f32x4 a = {};
      a = __builtin_amdgcn_mfma_f32_16x16x32_bf16(aQ0, b0, a, 0, 0, 0);
      a = __builtin_amdgcn_mfma_f32_16x16x32_bf16(aQ1, b1, a, 0, 0, 0);
      sv[jt] = a;
    }

#pragma unroll
    for (int r = 0; r < 4; ++r) {
      const int qa = q0 + wave * 16 + lq * 4 + r;
      float sr[8];
      float mx = -3.0e38f;
#pragma unroll
      for (int jt = 0; jt < 8; ++jt) {
        const int k = s0 + jt * 16 + lm;
        const float x = sv[jt][r] * 0.125f;
        const bool msk = (Ts[k] == 0) || (causal && (k > qa));
        sr[jt] = msk ? -1.0e18f : x;
        mx = fmaxf(mx, sr[jt]);
      }
#pragma unroll
      for (int o = 1; o < 16; o <<= 1) mx = fmaxf(mx, __shfl_xor(mx, o, 64));
      const float mn = fmaxf(m_i[r], mx);
      const float alpha = __expf(m_i[r] - mn);
      float sum = 0.0f;
#pragma unroll
      for (int jt = 0; jt < 8; ++jt) {
        const float pv = __expf(sr[jt] - mn);
        sr[jt] = pv;
        sum += pv;
      }
#pragma unroll
      for (int o = 1; o < 16; o <<= 1) sum += __shfl_xor(sum, o, 64);
      l_i[r] = l_i[r] * alpha + sum;
      m_i[r] = mn;
#pragma unroll
      for (int jn = 0; jn < 4; ++jn) O[jn][r] *= alpha;
#pragma unroll
      for (int jt = 0; jt < 8; ++jt)
        Ps[(wave * 16 + lq * 4 + r) * VPAD + jt * 16 + lm] = (bf16_t)sr[jt];
    }

#pragma unroll
    for (int kt = 0; kt < 4; ++kt) {
      const bf16x8 aP = *(const bf16x8*)&Ps[(wave * 16 + lm) * VPAD + kt * 32 + lq * 8];
#pragma unroll
      for (int jn = 0; jn < 4; ++jn) {
        const bf16x8 bV = *(const bf16x8*)&Vs[(jn * 16 + lm) * VPAD + kt * 32 + lq * 8];
        O[jn] = __builtin_amdgcn_mfma_f32_16x16x32_bf16(aP, bV, O[jn], 0, 0, 0);
      }
    }
  }

#pragma unroll
  for (int r = 0; r < 4; ++r) {
    const int q = q0 + wave * 16 + lq * 4 + r;
    const float inv = 1.0f / l_i[r];
#pragma unroll
    for (int jn = 0; jn < 4; ++jn) {
      const int d = jn * 16 + lm;
      ctx[(rowbase + q) * DMODEL + h * DHEAD + d] = (bf16_t)(O[jn][r] * inv);
    }
  }
}

// ---------- LayerNorm (row = 768) ----------
__global__ __launch_bounds__(256) void ln_kernel(const float* __restrict__ X,
                                                 const float* __restrict__ g,
                                                 const float* __restrict__ b,
                                                 bf16_t* __restrict__ outB,
                                                 float* __restrict__ outF) {
  const int row = blockIdx.x, tid = threadIdx.x;
  const float* xr = X + (long)row * DMODEL;
  const float v0 = xr[tid], v1 = xr[tid + 256], v2 = xr[tid + 512];
  __shared__ float r1[4], r2[4];
  const int wv = tid >> 6, ln = tid & 63;
  float s = wsum(v0 + v1 + v2);
  if (ln == 0) r1[wv] = s;
  __syncthreads();
  const float mean = (r1[0] + r1[1] + r1[2] + r1[3]) * (1.0f / DMODEL);
  const float d0 = v0 - mean, d1 = v1 - mean, d2 = v2 - mean;
  float q = wsum(d0 * d0 + d1 * d1 + d2 * d2);
  if (ln == 0) r2[wv] = q;
  __syncthreads();
  const float var = (r2[0] + r2[1] + r2[2] + r2[3]) * (1.0f / DMODEL);
  const float rs = rsqrtf(var + 1e-6f);
  const float y0 = d0 * rs * g[tid] + b[tid];
  const float y1 = d1 * rs * g[tid + 256] + b[tid + 256];
  const float y2 = d2 * rs * g[tid + 512] + b[tid + 512];
  const long base = (long)row * DMODEL;
  if (outB) {
    outB[base + tid] = (bf16_t)y0;
    outB[base + tid + 256] = (bf16_t)y1;
    outB[base + tid + 512] = (bf16_t)y2;
  }
  if (outF) {
    outF[base + tid] = y0;
    outF[base + tid + 256] = y1;
    outF[base + tid + 512] = y2;
  }
}

// ---------- reduce split-K partials + bias + residual, then LayerNorm ----------
__global__ __launch_bounds__(256) void reduce_ln_kernel(
    const float* __restrict__ parts, long pstr, int np,
    const float* __restrict__ bias, float* __restrict__ res,
    const float* __restrict__ g, const float* __restrict__ b,
    bf16_t* __restrict__ outB, float* __restrict__ outF) {
  const int row = blockIdx.x, tid = threadIdx.x;
  const long base = (long)row * DMODEL;
  float v0, v1, v2;
  {
    float t0 = res[base + tid] + bias[tid];
    float t1 = res[base + tid + 256] + bias[tid + 256];
    float t2 = res[base + tid + 512] + bias[tid + 512];
    for (int p = 0; p < np; ++p) {
      const float* pp = parts + p * pstr + base;
      t0 += pp[tid];
      t1 += pp[tid + 256];
      t2 += pp[tid + 512];
    }
    v0 = t0; v1 = t1; v2 = t2;
    res[base + tid] = t0;
    res[base + tid + 256] = t1;
    res[base + tid + 512] = t2;
  }
  __shared__ float r1[4], r2[4];
  const int wv = tid >> 6, ln = tid & 63;
  float s = wsum(v0 + v1 + v2);
  if (ln == 0) r1[wv] = s;
  __syncthreads();
  const float mean = (r1[0] + r1[1] + r1[2] + r1[3]) * (1.0f / DMODEL);
  const float d0 = v0 - mean, d1 = v1 - mean, d2 = v2 - mean;
  float q = wsum(d0 * d0 + d1 * d1 + d2 * d2);
  if (ln == 0) r2[wv] = q;
  __syncthreads();
  const float var = (r2[0] + r2[1] + r2[2] + r2[3]) * (1.0f / DMODEL);
  const float rs = rsqrtf(var + 1e-6f);
  const float y0 = d0 * rs * g[tid] + b[tid];
  const float y1 = d1 * rs * g[tid + 256] + b[tid + 256];
  const float y2 = d2 * rs * g[tid + 512] + b[tid + 512];
  if (outB) {
    outB[base + tid] = (bf16_t)y0;
    outB[base + tid + 256] = (bf16_t)y1;
    outB[base + tid + 512] = (bf16_t)y2;
  }
  if (outF) {
    outF[base + tid] = y0;
    outF[base + tid + 256] = y1;
    outF[base + tid + 512] = y2;
  }
}

// ---------- reduce split-K partials + bias -> strided bf16 (CA-q into qkv) ----------
__global__ __launch_bounds__(256) void reduce_cvtq_kernel(
    const float* __restrict__ parts, long pstr, int np,
    const float* __restrict__ bias, bf16_t* __restrict__ o) {
  const int row = blockIdx.x, tid = threadIdx.x;
  const long base = (long)row * DMODEL;
  const long ob = (long)row * 3 * DMODEL;
#pragma unroll
  for (int c = 0; c < 3; ++c) {
    const int col = tid + c * 256;
    float t = bias[col];
    for (int p = 0; p < np; ++p) t += parts[p * pstr + base + col];
    o[ob + col] = (bf16_t)t;
  }
}

// ---------- embedding * sqrt(D) + sinusoidal PE ----------
__global__ __launch_bounds__(256) void emb_kernel(const int* __restrict__ tgt,
                                                  const float* __restrict__ tab,
                                                  float* __restrict__ res) {
  const int row = blockIdx.x;
  const int t = row & (SEQ - 1);
  const long tok = tgt[row];
  const float* er = tab + tok * DMODEL;
  float* orow = res + (long)row * DMODEL;
  const float c1 = -9.210340371976184f / 768.0f;
  for (int c = threadIdx.x; c < DMODEL; c += 256) {
    const float e = er[c] * 27.712812921102035f;
    const float div = expf((float)(c & ~1) * c1);
    const float ang = (float)t * div;
    const float pe = (c & 1) ? cosf(ang) : sinf(ang);
    orow[c] = e + pe;
  }
}

// ---------- f32 -> bf16 convert (n4 = n/4) ----------
__global__ __launch_bounds__(256) void cvt_kernel(const float* __restrict__ in,
                                                  bf16_t* __restrict__ o, int n4) {
  const int i = blockIdx.x * 256 + threadIdx.x;
  if (i < n4) {
    const float4 v = ((const float4*)in)[i];
    bf16x4 r = {(bf16_t)v.x, (bf16_t)v.y, (bf16_t)v.z, (bf16_t)v.w};
    ((bf16x4*)o)[i] = r;
  }
}

// ---------- host ----------
extern "C" void kernel_launch(void* const* d_in, const int* in_sizes, int n_in,
                              void* d_out, int out_size, void* d_ws, size_t ws_size,
                              hipStream_t stream) {
  (void)in_sizes; (void)n_in; (void)out_size; (void)ws_size;
  const int* tgt = (const int*)d_in[0];
  const int* srct = (const int*)d_in[1];
  const float* memb = (const float*)d_in[2];
  const float* embt = (const float*)d_in[3];
  const float* sa_w = (const float*)d_in[4];
  const float* sa_b = (const float*)d_in[5];
  const float* ca_w = (const float*)d_in[6];
  const float* ca_b = (const float*)d_in[7];
  const float* ln_g = (const float*)d_in[8];
  const float* ln_b = (const float*)d_in[9];
  const float* ff_w1 = (const float*)d_in[10];
  const float* ff_b1 = (const float*)d_in[11];
  const float* ff_w2 = (const float*)d_in[12];
  const float* ff_b2 = (const float*)d_in[13];
  const float* out_g = (const float*)d_in[14];
  const float* out_b = (const float*)d_in[15];
  float* out = (float*)d_out;

  char* wsb = (char*)d_ws;
  size_t off = 0;
  auto alloc = [&](size_t bytes) -> void* {
    void* pp = wsb + off;
    off = (off + bytes + 255) & ~(size_t)255;
    return pp;
  };
  // Allocation ORDER/SIZES load-bearing: ksplit=4 partials span
  // parts(2*PSTR) + xb + qkvb exactly (xb+qkvb are DEAD at every ksplit=4
  // GEMM: all LN outputs live in ctxb, never xb).
  float* res = (float*)alloc((size_t)MROWS * DMODEL * 4);
  float* parts = (float*)alloc((size_t)2 * MROWS * DMODEL * 4);  // partials 0..1
  bf16_t* xb = (bf16_t*)alloc((size_t)MROWS * DMODEL * 2);       // partial 2 space
  bf16_t* qkvb = (bf16_t*)alloc((size_t)MROWS * 3 * DMODEL * 2); // partial 2/3 space
  bf16_t* ctxb = (bf16_t*)alloc((size_t)MROWS * DMODEL * 2);
  bf16_t* membb = (bf16_t*)alloc((size_t)MROWS * DMODEL * 2);
  bf16_t* ffh = (bf16_t*)alloc((size_t)MROWS * DFFN * 2);
  bf16_t* wA = (bf16_t*)alloc((size_t)4 * DMODEL * DMODEL * 2);
  bf16_t* wF1 = (bf16_t*)alloc((size_t)DFFN * DMODEL * 2);
  bf16_t* wF2 = (bf16_t*)alloc((size_t)DFFN * DMODEL * 2);
  (void)xb;

  const long PSTR = (long)MROWS * DMODEL;

  auto gemm = [&](const bf16_t* A, const bf16_t* Bm, const float* bias,
                  float* oF, bf16_t* oB, int M, int N, int K,
                  int lda, int ldb, int ldc, int act, int ksplit) {
    GP p{A, Bm, bias, oF, oB, M, N, K, lda, ldb, ldc, PSTR, act, ksplit};
    dim3 g((unsigned)(M / 128), (unsigned)(N / 128), (unsigned)ksplit);
    gemm128<<<g, 256, 0, stream>>>(p);
  };

  const long WSZ = (long)DMODEL * DMODEL;

  emb_kernel<<<MROWS, 256, 0, stream>>>(tgt, embt, res);
  cvt_kernel<<<(MROWS * DMODEL / 4 + 255) / 256, 256, 0, stream>>>(memb, membb,
                                                                   MROWS * DMODEL / 4);
  ln_kernel<<<MROWS, 256, 0, stream>>>(res, ln_g, ln_b, ctxb, nullptr);

  for (int l = 0; l < NLAYER; ++l) {
    const float* saw = sa_w + (long)l * 4 * WSZ;
    const float* sab = sa_b + (long)l * 4 * DMODEL;
    const float* caw = ca_w + (long)l * 4 * WSZ;
    const float* cab = ca_b + (long)l * 4 * DMODEL;

    // ======== self-attention ========   (ctxb = ln1)
    cvt_kernel<<<(int)((WSZ + 255) / 256), 256, 0, stream>>>(saw, wA, (int)WSZ);
    gemm(ctxb, wA, sab, nullptr, qkvb, MROWS, 3 * DMODEL, DMODEL,
         DMODEL, DMODEL, 3 * DMODEL, 0, 1);
    attn_kernel<<<dim3(SEQ / QT, BATCH * NHEAD), 256, 0, stream>>>(qkvb, tgt, ctxb, 1);
    // SA-out: ksplit=4 (xb/qkvb dead -> partials 2,3 alias them)
    gemm(ctxb, wA + 3 * WSZ, nullptr, parts, nullptr, MROWS, DMODEL, DMODEL,
         DMODEL, DMODEL, DMODEL, 0, 4);
    reduce_ln_kernel<<<MROWS, 256, 0, stream>>>(parts, PSTR, 4, sab + 3 * DMODEL, res,
                                                ln_g + (l * 3 + 1) * DMODEL,
                                                ln_b + (l * 3 + 1) * DMODEL, ctxb, nullptr);

    // ======== cross-attention ========  (ctxb = ln2)
    cvt_kernel<<<(int)((WSZ + 255) / 256), 256, 0, stream>>>(caw, wA, (int)WSZ);
    // CA-q stays ksplit=2 (its reduce writes qkvb, which aliases partials 2,3)
    gemm(ctxb, wA, nullptr, parts, nullptr, MROWS, DMODEL, DMODEL,
         DMODEL, DMODEL, DMODEL, 0, 2);
    reduce_cvtq_kernel<<<MROWS, 256, 0, stream>>>(parts, PSTR, 2, cab, qkvb);
    gemm(membb, wA + WSZ, cab + DMODEL, nullptr, qkvb + DMODEL, MROWS,
         2 * DMODEL, DMODEL, DMODEL, DMODEL, 3 * DMODEL, 0, 1);
    attn_kernel<<<dim3(SEQ / QT, BATCH * NHEAD), 256, 0, stream>>>(qkvb, srct, ctxb, 0);
    // CA-out: ksplit=4 (xb/qkvb dead again)
    gemm(ctxb, wA + 3 * WSZ, nullptr, parts, nullptr, MROWS, DMODEL, DMODEL,
         DMODEL, DMODEL, DMODEL, 0, 4);
    reduce_ln_kernel<<<MROWS, 256, 0, stream>>>(parts, PSTR, 4, cab + 3 * DMODEL, res,
                                                ln_g + (l * 3 + 2) * DMODEL,
                                                ln_b + (l * 3 + 2) * DMODEL, ctxb, nullptr);

    // ======== FFN ========  (ctxb = ln3)
    cvt_kernel<<<(int)((DFFN * (long)DMODEL / 4 + 255) / 256), 256, 0, stream>>>(
        ff_w1 + (long)l * DFFN * DMODEL, wF1, (int)(DFFN * (long)DMODEL / 4));
    cvt_kernel<<<(int)((DFFN * (long)DMODEL / 4 + 255) / 256), 256, 0, stream>>>(
        ff_w2 + (long)l * DFFN * DMODEL, wF2, (int)(DFFN * (long)DMODEL / 4));
    gemm(ctxb, wF1, ff_b1 + (long)l * DFFN, nullptr, ffh, MROWS, DFFN,
         DMODEL, DMODEL, DMODEL, DFFN, 1, 1);
    gemm(ffh, wF2, nullptr, parts, nullptr, MROWS, DMODEL, DFFN,
         DFFN, DFFN, DMODEL, 0, 4);
    if (l < NLAYER - 1) {
      reduce_ln_kernel<<<MROWS, 256, 0, stream>>>(parts, PSTR, 4, ff_b2 + (long)l * DMODEL,
                                                  res, ln_g + ((l + 1) * 3) * DMODEL,
                                                  ln_b + ((l + 1) * 3) * DMODEL, ctxb, nullptr);
    } else {
      reduce_ln_kernel<<<MROWS, 256, 0, stream>>>(parts, PSTR, 4, ff_b2 + (long)l * DMODEL,
                                                  res, out_g, out_b, nullptr, out);
    }
  }
}